// Round 5
// baseline (546.181 us; speedup 1.0000x reference)
//
#include <hip/hip_runtime.h>

#define DIM 32
#define EPB 8192      // edges per binA block
#define BSH 7         // bucket shift: 128 dsts per bucket
#define BDST 128
#define MAXB 1024     // max buckets supported by LDS tables (N <= 131072)

__global__ void zero_kernel(int* __restrict__ p, int n) {
    int i = blockIdx.x * blockDim.x + threadIdx.x;
    if (i < n) p[i] = 0;
}

__global__ void dis_kernel(const int* __restrict__ deg, float* __restrict__ dis, int n) {
    int i = blockIdx.x * blockDim.x + threadIdx.x;
    if (i < n) dis[i] = rsqrtf((float)deg[i] + 1.0f);  // +1 self-loop
}

// hs[row] = (x @ W)[row] * dis[row]
__global__ void gemm_kernel(const float* __restrict__ x, const float* __restrict__ W,
                            const float* __restrict__ dis, float* __restrict__ hs, int n) {
    __shared__ float Ws[DIM * DIM];
    int tid = threadIdx.x;
    for (int i = tid; i < DIM * DIM; i += blockDim.x) Ws[i] = W[i];
    __syncthreads();
    int row = blockIdx.x * (blockDim.x / DIM) + (tid >> 5);
    int col = tid & 31;
    if (row < n) {
        const float* xr = x + row * DIM;
        float s = 0.f;
#pragma unroll
        for (int k = 0; k < DIM; ++k) s += xr[k] * Ws[k * DIM + col];
        hs[row * DIM + col] = s * dis[row];
    }
}

// Pass A: per 8192-edge chunk — local bucket-sort into private global region
// (all global writes coalesced; no global cursors). Fused global deg count.
__global__ __launch_bounds__(256) void binA_kernel(
        const int* __restrict__ src, const int* __restrict__ dst,
        int* __restrict__ deg, unsigned int* __restrict__ packed,
        unsigned short* __restrict__ tbl, int E, int NB) {
    __shared__ unsigned int H[MAXB], S1[MAXB], S2[MAXB];
    __shared__ unsigned int stage[EPB];
    int t = threadIdx.x;
    int base = blockIdx.x * EPB;
    int cnt = min(EPB, E - base);

    for (int i = t; i < NB; i += 256) H[i] = 0u;
    __syncthreads();

    // histogram over buckets + global degree count
#pragma unroll
    for (int k = 0; k < EPB / 256; ++k) {
        int idx = t + k * 256;
        if (idx < cnt) {
            int d = dst[base + idx];
            atomicAdd(&H[d >> BSH], 1u);
            atomicAdd(&deg[d], 1);
        }
    }
    __syncthreads();

    // inclusive scan of H (Hillis-Steele, double-buffered, strided)
    unsigned int* A = S1;
    unsigned int* Bp = S2;
    for (int i = t; i < NB; i += 256) A[i] = H[i];
    __syncthreads();
    for (int off = 1; off < NB; off <<= 1) {
        for (int i = t; i < NB; i += 256)
            Bp[i] = A[i] + ((i >= off) ? A[i - off] : 0u);
        __syncthreads();
        unsigned int* tmp = A; A = Bp; Bp = tmp;
    }
    // A = inclusive scan; exclusive into Bp (same strided mapping -> no race)
    for (int i = t; i < NB; i += 256) Bp[i] = A[i] - H[i];

    // write offset table row: excl offsets + total sentinel
    unsigned short* row = tbl + (size_t)blockIdx.x * (NB + 1);
    for (int i = t; i < NB; i += 256) row[i] = (unsigned short)Bp[i];
    if (t == 0) row[NB] = (unsigned short)cnt;
    __syncthreads();  // table reads of Bp complete before cursor mutation

    // scatter packed edges into LDS stage via LDS cursors
#pragma unroll
    for (int k = 0; k < EPB / 256; ++k) {
        int idx = t + k * 256;
        if (idx < cnt) {
            int d = dst[base + idx];
            int s = src[base + idx];
            unsigned int pos = atomicAdd(&Bp[d >> BSH], 1u);
            stage[pos] = ((unsigned int)s << BSH) | (unsigned int)(d & (BDST - 1));
        }
    }
    __syncthreads();

    // coalesced copy-out
#pragma unroll
    for (int k = 0; k < EPB / 256; ++k) {
        int idx = t + k * 256;
        if (idx < cnt) packed[base + idx] = stage[idx];
    }
}

// Pass B: one block per bucket (128 dsts). Stream fragments, gather hs[src],
// LDS-accumulate, fused dis/bias/NodeNorm/LeakyReLU epilogue.
__global__ __launch_bounds__(256) void aggB_kernel(
        const unsigned int* __restrict__ packed, const unsigned short* __restrict__ tbl,
        const float* __restrict__ hs, const float* __restrict__ dis,
        const float* __restrict__ bias, float* __restrict__ out,
        int N, int NB, int nblkA) {
    __shared__ float accum[BDST * DIM];  // 16 KB
    int t = threadIdx.x;
    for (int i = t; i < BDST * DIM; i += 256) accum[i] = 0.f;
    __syncthreads();

    int b = blockIdx.x;
    int wave = t >> 6;
    int lane = t & 63;
    int g = lane >> 5;   // which of 2 edge slots
    int f = lane & 31;   // feature

    for (int frag = wave; frag < nblkA; frag += 4) {
        const unsigned short* row = tbl + (size_t)frag * (NB + 1);
        int start = row[b];
        int end = row[b + 1];
        int base = frag * EPB;
        for (int j = start; j < end; j += 4) {
            int j0 = j + g, j1 = j + 2 + g;
            bool v0 = j0 < end, v1 = j1 < end;
            unsigned int p0 = v0 ? packed[base + j0] : 0u;
            unsigned int p1 = v1 ? packed[base + j1] : 0u;
            float h0 = v0 ? hs[(size_t)(p0 >> BSH) * DIM + f] : 0.f;
            float h1 = v1 ? hs[(size_t)(p1 >> BSH) * DIM + f] : 0.f;
            if (v0) atomicAdd(&accum[(p0 & (BDST - 1)) * DIM + f], h0);
            if (v1) atomicAdd(&accum[(p1 & (BDST - 1)) * DIM + f], h1);
        }
    }
    __syncthreads();

    // epilogue: 8 dsts x 32 feats per iteration
    int grp = t >> 5;  // 0..7
    float bf = bias[f];
    for (int r = 0; r < BDST / 8; ++r) {
        int dL = r * 8 + grp;
        int d = b * BDST + dL;
        if (d < N) {
            float v = dis[d] * (accum[dL * DIM + f] + hs[(size_t)d * DIM + f]) + bf;
            float s1 = v, s2 = v * v;
#pragma unroll
            for (int off = 16; off > 0; off >>= 1) {
                s1 += __shfl_xor(s1, off, 32);
                s2 += __shfl_xor(s2, off, 32);
            }
            float mean = s1 * (1.0f / 32.0f);
            float var = fmaxf(s2 * (1.0f / 32.0f) - mean * mean, 0.f);
            float o = (v - mean) * rsqrtf(var + 1e-6f);
            out[(size_t)d * DIM + f] = (o >= 0.f) ? o : 0.01f * o;
        }
    }
}

extern "C" void kernel_launch(void* const* d_in, const int* in_sizes, int n_in,
                              void* d_out, int out_size, void* d_ws, size_t ws_size,
                              hipStream_t stream) {
    const float* x = (const float*)d_in[0];
    const int* edge_index = (const int*)d_in[1];
    const float* W = (const float*)d_in[2];
    const float* b = (const float*)d_in[3];
    float* out = (float*)d_out;

    const int N = in_sizes[0] / DIM;      // 100000
    const int E = in_sizes[1] / 2;        // 1600000
    const int* src = edge_index;
    const int* dst = edge_index + E;

    const int NB = (N + BDST - 1) / BDST;       // 782 buckets
    const int nblkA = (E + EPB - 1) / EPB;      // 196 chunks

    char* w = (char*)d_ws;
    float* hs            = (float*)w;  w += (size_t)N * DIM * sizeof(float);
    unsigned int* packed = (unsigned int*)w;  w += (size_t)E * sizeof(unsigned int);
    unsigned short* tbl  = (unsigned short*)w;
    size_t tbl_bytes = ((size_t)nblkA * (NB + 1) * sizeof(unsigned short) + 3) & ~(size_t)3;
    w += tbl_bytes;
    int* deg   = (int*)w;   w += (size_t)N * sizeof(int);
    float* dis = (float*)w; w += (size_t)N * sizeof(float);

    zero_kernel<<<(N + 255) / 256, 256, 0, stream>>>(deg, N);
    binA_kernel<<<nblkA, 256, 0, stream>>>(src, dst, deg, packed, tbl, E, NB);
    dis_kernel<<<(N + 255) / 256, 256, 0, stream>>>(deg, dis, N);
    gemm_kernel<<<(N + 7) / 8, 256, 0, stream>>>(x, W, dis, hs, N);
    aggB_kernel<<<NB, 256, 0, stream>>>(packed, tbl, hs, dis, b, out, N, NB, nblkA);
}

// Round 6
// 513.877 us; speedup vs baseline: 1.0629x; 1.0629x over previous
//
#include <hip/hip_runtime.h>

#define DIM 32
#define EPB 8192      // edges per binA chunk
#define BSH 6         // 64 dsts per bucket
#define BDST 64
#define MAXB 1600     // >= NB = ceil(N/64) = 1563
#define SCAN_B 256

__global__ void zero_kernel(int* __restrict__ p, int n) {
    int i = blockIdx.x * blockDim.x + threadIdx.x;
    if (i < n) p[i] = 0;
}

// ---- Pass A: per-chunk bucket sort (coalesced in/out) + global deg count ----
__global__ __launch_bounds__(256) void binA_kernel(
        const int* __restrict__ src, const int* __restrict__ dst,
        int* __restrict__ deg, unsigned int* __restrict__ packed,
        unsigned short* __restrict__ bucketId,
        unsigned short* __restrict__ tbl, unsigned short* __restrict__ cnts,
        int E, int NB) {
    __shared__ unsigned int H[MAXB], S1[MAXB], S2[MAXB];
    __shared__ unsigned int stage[EPB];
    __shared__ unsigned short stageB[EPB];
    int t = threadIdx.x;
    int base = blockIdx.x * EPB;
    int cnt = min(EPB, E - base);

    for (int i = t; i < NB; i += 256) H[i] = 0u;
    __syncthreads();

#pragma unroll
    for (int k = 0; k < EPB / 256; ++k) {
        int idx = t + k * 256;
        if (idx < cnt) {
            int d = dst[base + idx];
            atomicAdd(&H[d >> BSH], 1u);
            atomicAdd(&deg[d], 1);
        }
    }
    __syncthreads();

    // Hillis-Steele inclusive scan (double-buffered, strided)
    unsigned int* A = S1;
    unsigned int* Bp = S2;
    for (int i = t; i < NB; i += 256) A[i] = H[i];
    __syncthreads();
    for (int off = 1; off < NB; off <<= 1) {
        for (int i = t; i < NB; i += 256)
            Bp[i] = A[i] + ((i >= off) ? A[i - off] : 0u);
        __syncthreads();
        unsigned int* tmp = A; A = Bp; Bp = tmp;
    }
    for (int i = t; i < NB; i += 256) Bp[i] = A[i] - H[i];  // exclusive

    unsigned short* row = tbl + (size_t)blockIdx.x * (NB + 1);
    unsigned short* crow = cnts + (size_t)blockIdx.x * NB;
    for (int i = t; i < NB; i += 256) {
        row[i] = (unsigned short)Bp[i];
        crow[i] = (unsigned short)H[i];
    }
    if (t == 0) row[NB] = (unsigned short)cnt;
    __syncthreads();  // Bp reads done before cursor mutation

#pragma unroll
    for (int k = 0; k < EPB / 256; ++k) {
        int idx = t + k * 256;
        if (idx < cnt) {
            int d = dst[base + idx];
            int s = src[base + idx];
            int b = d >> BSH;
            unsigned int pos = atomicAdd(&Bp[b], 1u);
            stage[pos] = ((unsigned int)s << BSH) | (unsigned int)(d & (BDST - 1));
            stageB[pos] = (unsigned short)b;
        }
    }
    __syncthreads();

#pragma unroll
    for (int k = 0; k < EPB / 256; ++k) {
        int idx = t + k * 256;
        if (idx < cnt) {
            packed[base + idx] = stage[idx];
            bucketId[base + idx] = stageB[idx];
        }
    }
}

// ---- deg scan -> rowptr (+ fused dis) ----
__global__ void partial_kernel(const int* __restrict__ deg, int* __restrict__ partials, int n) {
    __shared__ int s[SCAN_B];
    int t = threadIdx.x;
    int i = blockIdx.x * SCAN_B + t;
    s[t] = (i < n) ? deg[i] : 0;
    __syncthreads();
    for (int off = SCAN_B / 2; off > 0; off >>= 1) {
        if (t < off) s[t] += s[t + off];
        __syncthreads();
    }
    if (t == 0) partials[blockIdx.x] = s[0];
}

__global__ void scan_partials_kernel(int* __restrict__ partials, int nb) {
    __shared__ int s[512];
    int t = threadIdx.x;
    int v = (t < nb) ? partials[t] : 0;
    s[t] = v;
    __syncthreads();
    for (int off = 1; off < 512; off <<= 1) {
        int x = (t >= off) ? s[t - off] : 0;
        __syncthreads();
        s[t] += x;
        __syncthreads();
    }
    if (t < nb) partials[t] = s[t] - v;
}

__global__ void scan_kernel(const int* __restrict__ deg, const int* __restrict__ partials,
                            int* __restrict__ rowptr, float* __restrict__ dis, int n) {
    __shared__ int s[SCAN_B];
    int t = threadIdx.x;
    int i = blockIdx.x * SCAN_B + t;
    int v = (i < n) ? deg[i] : 0;
    s[t] = v;
    __syncthreads();
    for (int off = 1; off < SCAN_B; off <<= 1) {
        int x = (t >= off) ? s[t - off] : 0;
        __syncthreads();
        s[t] += x;
        __syncthreads();
    }
    if (i < n) {
        int excl = s[t] - v + partials[blockIdx.x];
        rowptr[i] = excl;
        dis[i] = rsqrtf((float)v + 1.0f);
        if (i == n - 1) rowptr[n] = excl + v;
    }
}

// ---- per (chunk,bucket) global slice offsets: one wave per bucket ----
__global__ __launch_bounds__(256) void gofs_kernel(
        const unsigned short* __restrict__ cnts, const int* __restrict__ rowptr,
        unsigned int* __restrict__ gofs, int NB, int nfrag) {
    int wave = threadIdx.x >> 6, lane = threadIdx.x & 63;
    int b = blockIdx.x * 4 + wave;
    if (b >= NB) return;
    unsigned int c[4], e[4];
#pragma unroll
    for (int k = 0; k < 4; ++k) {
        int frag = lane * 4 + k;
        c[k] = (frag < nfrag) ? (unsigned int)cnts[(size_t)frag * NB + b] : 0u;
    }
    e[0] = 0; e[1] = c[0]; e[2] = c[0] + c[1]; e[3] = e[2] + c[2];
    unsigned int laneSum = e[3] + c[3];
    unsigned int v = laneSum;
    for (int off = 1; off < 64; off <<= 1) {
        unsigned int u = __shfl_up(v, off, 64);
        if (lane >= off) v += u;
    }
    unsigned int excl = v - laneSum;
    unsigned int bs = (unsigned int)rowptr[b * BDST];
#pragma unroll
    for (int k = 0; k < 4; ++k) {
        int frag = lane * 4 + k;
        if (frag < nfrag) gofs[(size_t)frag * NB + b] = bs + excl + e[k];
    }
}

// ---- scatter chunk-sorted edges into bucket-major final layout ----
__global__ __launch_bounds__(256) void copyout_kernel(
        const unsigned int* __restrict__ packed, const unsigned short* __restrict__ bucketId,
        const unsigned short* __restrict__ tbl, const unsigned int* __restrict__ gofs,
        unsigned int* __restrict__ packedF, int E, int NB) {
    __shared__ unsigned short rowL[MAXB];
    __shared__ unsigned int gofsL[MAXB];
    int t = threadIdx.x;
    int frag = blockIdx.x;
    int base = frag * EPB;
    int cnt = min(EPB, E - base);
    const unsigned short* row = tbl + (size_t)frag * (NB + 1);
    const unsigned int* grow = gofs + (size_t)frag * NB;
    for (int i = t; i < NB; i += 256) { rowL[i] = row[i]; gofsL[i] = grow[i]; }
    __syncthreads();
#pragma unroll
    for (int k = 0; k < EPB / 256; ++k) {
        int idx = t + k * 256;
        if (idx < cnt) {
            int b = bucketId[base + idx];
            packedF[gofsL[b] + (unsigned int)(idx - (int)rowL[b])] = packed[base + idx];
        }
    }
}

// hs[row] = (x @ W)[row] * dis[row]
__global__ void gemm_kernel(const float* __restrict__ x, const float* __restrict__ W,
                            const float* __restrict__ dis, float* __restrict__ hs, int n) {
    __shared__ float Ws[DIM * DIM];
    int tid = threadIdx.x;
    for (int i = tid; i < DIM * DIM; i += blockDim.x) Ws[i] = W[i];
    __syncthreads();
    int row = blockIdx.x * (blockDim.x / DIM) + (tid >> 5);
    int col = tid & 31;
    if (row < n) {
        const float* xr = x + row * DIM;
        float s = 0.f;
#pragma unroll
        for (int k = 0; k < DIM; ++k) s += xr[k] * Ws[k * DIM + col];
        hs[row * DIM + col] = s * dis[row];
    }
}

// ---- aggregate: one block per bucket, contiguous edge run, LDS accum ----
__global__ __launch_bounds__(256) void agg_kernel(
        const unsigned int* __restrict__ packedF, const int* __restrict__ rowptr,
        const float* __restrict__ hs, const float* __restrict__ dis,
        const float* __restrict__ bias, float* __restrict__ out, int N) {
    __shared__ float accum[BDST * DIM];  // 8 KB
    int t = threadIdx.x;
    for (int i = t; i < BDST * DIM; i += 256) accum[i] = 0.f;
    __syncthreads();

    int b = blockIdx.x;
    int start = rowptr[b * BDST];
    int end = rowptr[min(b * BDST + BDST, N)];
    int len = end - start;
    int wave = t >> 6, lane = t & 63, g = lane >> 5, f = lane & 31;
    int q = (len + 3) >> 2;
    int ws = start + wave * q;
    int we = min(ws + q, end);

    for (int j = ws; j < we; j += 8) {
        unsigned int p[4]; float h[4]; bool val[4];
#pragma unroll
        for (int u = 0; u < 4; ++u) {
            int idx = j + 2 * u + g;
            val[u] = idx < we;
            p[u] = val[u] ? packedF[idx] : 0u;
        }
#pragma unroll
        for (int u = 0; u < 4; ++u)
            h[u] = val[u] ? hs[(size_t)(p[u] >> BSH) * DIM + f] : 0.f;
#pragma unroll
        for (int u = 0; u < 4; ++u)
            if (val[u]) atomicAdd(&accum[(p[u] & (BDST - 1)) * DIM + f], h[u]);
    }
    __syncthreads();

    int grp = t >> 5;  // 0..7
    float bf = bias[f];
    for (int r = 0; r < BDST / 8; ++r) {
        int dL = r * 8 + grp;
        int d = b * BDST + dL;
        if (d < N) {
            float v = dis[d] * (accum[dL * DIM + f] + hs[(size_t)d * DIM + f]) + bf;
            float s1 = v, s2 = v * v;
#pragma unroll
            for (int off = 16; off > 0; off >>= 1) {
                s1 += __shfl_xor(s1, off, 32);
                s2 += __shfl_xor(s2, off, 32);
            }
            float mean = s1 * (1.0f / 32.0f);
            float var = fmaxf(s2 * (1.0f / 32.0f) - mean * mean, 0.f);
            float o = (v - mean) * rsqrtf(var + 1e-6f);
            out[(size_t)d * DIM + f] = (o >= 0.f) ? o : 0.01f * o;
        }
    }
}

extern "C" void kernel_launch(void* const* d_in, const int* in_sizes, int n_in,
                              void* d_out, int out_size, void* d_ws, size_t ws_size,
                              hipStream_t stream) {
    const float* x = (const float*)d_in[0];
    const int* edge_index = (const int*)d_in[1];
    const float* W = (const float*)d_in[2];
    const float* b = (const float*)d_in[3];
    float* out = (float*)d_out;

    const int N = in_sizes[0] / DIM;      // 100000
    const int E = in_sizes[1] / 2;        // 1600000
    const int* src = edge_index;
    const int* dst = edge_index + E;

    const int NB = (N + BDST - 1) / BDST;       // 1563 buckets
    const int nblkA = (E + EPB - 1) / EPB;      // 196 chunks
    const int NBLK = (N + SCAN_B - 1) / SCAN_B; // 391

    char* w = (char*)d_ws;
    float* hs              = (float*)w;          w += (size_t)N * DIM * sizeof(float);
    unsigned int* packed   = (unsigned int*)w;   w += (size_t)E * sizeof(unsigned int);
    unsigned int* packedF  = (unsigned int*)w;   w += (size_t)E * sizeof(unsigned int);
    unsigned int* gofs     = (unsigned int*)w;   w += (size_t)nblkA * NB * sizeof(unsigned int);
    unsigned short* bucketId = (unsigned short*)w; w += (((size_t)E * 2 + 3) & ~(size_t)3);
    unsigned short* tbl    = (unsigned short*)w; w += (((size_t)nblkA * (NB + 1) * 2 + 3) & ~(size_t)3);
    unsigned short* cnts   = (unsigned short*)w; w += (((size_t)nblkA * NB * 2 + 3) & ~(size_t)3);
    int* deg     = (int*)w;   w += (size_t)N * sizeof(int);
    int* rowptr  = (int*)w;   w += (size_t)(N + 1) * sizeof(int);
    float* dis   = (float*)w; w += (size_t)N * sizeof(float);
    int* partials = (int*)w;  w += 1024 * sizeof(int);

    zero_kernel<<<(N + 255) / 256, 256, 0, stream>>>(deg, N);
    binA_kernel<<<nblkA, 256, 0, stream>>>(src, dst, deg, packed, bucketId, tbl, cnts, E, NB);
    partial_kernel<<<NBLK, SCAN_B, 0, stream>>>(deg, partials, N);
    scan_partials_kernel<<<1, 512, 0, stream>>>(partials, NBLK);
    scan_kernel<<<NBLK, SCAN_B, 0, stream>>>(deg, partials, rowptr, dis, N);
    gofs_kernel<<<(NB + 3) / 4, 256, 0, stream>>>(cnts, rowptr, gofs, NB, nblkA);
    gemm_kernel<<<(N + 7) / 8, 256, 0, stream>>>(x, W, dis, hs, N);
    copyout_kernel<<<nblkA, 256, 0, stream>>>(packed, bucketId, tbl, gofs, packedF, E, NB);
    agg_kernel<<<NB, 256, 0, stream>>>(packedF, rowptr, hs, dis, b, out, N);
}

// Round 7
// 511.940 us; speedup vs baseline: 1.0669x; 1.0038x over previous
//
#include <hip/hip_runtime.h>

#define DIM 32
#define EPB 8192      // edges per binA chunk
#define BSH 6         // 64 dsts per bucket
#define BDST 64
#define MAXB 1600     // >= NB = ceil(N/64) = 1563
#define SCAN_B 256

__global__ void zero_kernel(int* __restrict__ p, int n) {
    int i = blockIdx.x * blockDim.x + threadIdx.x;
    if (i < n) p[i] = 0;
}

// ---- Pass A: per-chunk bucket sort (coalesced in/out) + global deg count ----
__global__ __launch_bounds__(256) void binA_kernel(
        const int* __restrict__ src, const int* __restrict__ dst,
        int* __restrict__ deg, unsigned int* __restrict__ packed,
        unsigned short* __restrict__ bucketId,
        unsigned short* __restrict__ tbl, unsigned short* __restrict__ cnts,
        int E, int NB) {
    __shared__ unsigned int H[MAXB], S1[MAXB], S2[MAXB];
    __shared__ unsigned int stage[EPB];
    __shared__ unsigned short stageB[EPB];
    int t = threadIdx.x;
    int base = blockIdx.x * EPB;
    int cnt = min(EPB, E - base);

    for (int i = t; i < NB; i += 256) H[i] = 0u;
    __syncthreads();

#pragma unroll
    for (int k = 0; k < EPB / 256; ++k) {
        int idx = t + k * 256;
        if (idx < cnt) {
            int d = dst[base + idx];
            atomicAdd(&H[d >> BSH], 1u);
            atomicAdd(&deg[d], 1);
        }
    }
    __syncthreads();

    // Hillis-Steele inclusive scan (double-buffered, strided)
    unsigned int* A = S1;
    unsigned int* Bp = S2;
    for (int i = t; i < NB; i += 256) A[i] = H[i];
    __syncthreads();
    for (int off = 1; off < NB; off <<= 1) {
        for (int i = t; i < NB; i += 256)
            Bp[i] = A[i] + ((i >= off) ? A[i - off] : 0u);
        __syncthreads();
        unsigned int* tmp = A; A = Bp; Bp = tmp;
    }
    for (int i = t; i < NB; i += 256) Bp[i] = A[i] - H[i];  // exclusive

    unsigned short* row = tbl + (size_t)blockIdx.x * (NB + 1);
    unsigned short* crow = cnts + (size_t)blockIdx.x * NB;
    for (int i = t; i < NB; i += 256) {
        row[i] = (unsigned short)Bp[i];
        crow[i] = (unsigned short)H[i];
    }
    if (t == 0) row[NB] = (unsigned short)cnt;
    __syncthreads();  // Bp reads done before cursor mutation

#pragma unroll
    for (int k = 0; k < EPB / 256; ++k) {
        int idx = t + k * 256;
        if (idx < cnt) {
            int d = dst[base + idx];
            int s = src[base + idx];
            int b = d >> BSH;
            unsigned int pos = atomicAdd(&Bp[b], 1u);
            stage[pos] = ((unsigned int)s << BSH) | (unsigned int)(d & (BDST - 1));
            stageB[pos] = (unsigned short)b;
        }
    }
    __syncthreads();

#pragma unroll
    for (int k = 0; k < EPB / 256; ++k) {
        int idx = t + k * 256;
        if (idx < cnt) {
            packed[base + idx] = stage[idx];
            bucketId[base + idx] = stageB[idx];
        }
    }
}

// ---- deg scan -> rowptr (+ fused dis) ----
__global__ void partial_kernel(const int* __restrict__ deg, int* __restrict__ partials, int n) {
    __shared__ int s[SCAN_B];
    int t = threadIdx.x;
    int i = blockIdx.x * SCAN_B + t;
    s[t] = (i < n) ? deg[i] : 0;
    __syncthreads();
    for (int off = SCAN_B / 2; off > 0; off >>= 1) {
        if (t < off) s[t] += s[t + off];
        __syncthreads();
    }
    if (t == 0) partials[blockIdx.x] = s[0];
}

__global__ void scan_partials_kernel(int* __restrict__ partials, int nb) {
    __shared__ int s[512];
    int t = threadIdx.x;
    int v = (t < nb) ? partials[t] : 0;
    s[t] = v;
    __syncthreads();
    for (int off = 1; off < 512; off <<= 1) {
        int x = (t >= off) ? s[t - off] : 0;
        __syncthreads();
        s[t] += x;
        __syncthreads();
    }
    if (t < nb) partials[t] = s[t] - v;
}

__global__ void scan_kernel(const int* __restrict__ deg, const int* __restrict__ partials,
                            int* __restrict__ rowptr, float* __restrict__ dis, int n) {
    __shared__ int s[SCAN_B];
    int t = threadIdx.x;
    int i = blockIdx.x * SCAN_B + t;
    int v = (i < n) ? deg[i] : 0;
    s[t] = v;
    __syncthreads();
    for (int off = 1; off < SCAN_B; off <<= 1) {
        int x = (t >= off) ? s[t - off] : 0;
        __syncthreads();
        s[t] += x;
        __syncthreads();
    }
    if (i < n) {
        int excl = s[t] - v + partials[blockIdx.x];
        rowptr[i] = excl;
        dis[i] = rsqrtf((float)v + 1.0f);
        if (i == n - 1) rowptr[n] = excl + v;
    }
}

// ---- per (chunk,bucket) global slice offsets: one wave per bucket ----
__global__ __launch_bounds__(256) void gofs_kernel(
        const unsigned short* __restrict__ cnts, const int* __restrict__ rowptr,
        unsigned int* __restrict__ gofs, int NB, int nfrag) {
    int wave = threadIdx.x >> 6, lane = threadIdx.x & 63;
    int b = blockIdx.x * 4 + wave;
    if (b >= NB) return;
    unsigned int c[4], e[4];
#pragma unroll
    for (int k = 0; k < 4; ++k) {
        int frag = lane * 4 + k;
        c[k] = (frag < nfrag) ? (unsigned int)cnts[(size_t)frag * NB + b] : 0u;
    }
    e[0] = 0; e[1] = c[0]; e[2] = c[0] + c[1]; e[3] = e[2] + c[2];
    unsigned int laneSum = e[3] + c[3];
    unsigned int v = laneSum;
    for (int off = 1; off < 64; off <<= 1) {
        unsigned int u = __shfl_up(v, off, 64);
        if (lane >= off) v += u;
    }
    unsigned int excl = v - laneSum;
    unsigned int bs = (unsigned int)rowptr[b * BDST];
#pragma unroll
    for (int k = 0; k < 4; ++k) {
        int frag = lane * 4 + k;
        if (frag < nfrag) gofs[(size_t)frag * NB + b] = bs + excl + e[k];
    }
}

// ---- scatter chunk-sorted edges into bucket-major final layout ----
__global__ __launch_bounds__(256) void copyout_kernel(
        const unsigned int* __restrict__ packed, const unsigned short* __restrict__ bucketId,
        const unsigned short* __restrict__ tbl, const unsigned int* __restrict__ gofs,
        unsigned int* __restrict__ packedF, int E, int NB) {
    __shared__ unsigned short rowL[MAXB];
    __shared__ unsigned int gofsL[MAXB];
    int t = threadIdx.x;
    int frag = blockIdx.x;
    int base = frag * EPB;
    int cnt = min(EPB, E - base);
    const unsigned short* row = tbl + (size_t)frag * (NB + 1);
    const unsigned int* grow = gofs + (size_t)frag * NB;
    for (int i = t; i < NB; i += 256) { rowL[i] = row[i]; gofsL[i] = grow[i]; }
    __syncthreads();
#pragma unroll
    for (int k = 0; k < EPB / 256; ++k) {
        int idx = t + k * 256;
        if (idx < cnt) {
            int b = bucketId[base + idx];
            packedF[gofsL[b] + (unsigned int)(idx - (int)rowL[b])] = packed[base + idx];
        }
    }
}

// hs[row] = (x @ W)[row] * dis[row]
__global__ void gemm_kernel(const float* __restrict__ x, const float* __restrict__ W,
                            const float* __restrict__ dis, float* __restrict__ hs, int n) {
    __shared__ float Ws[DIM * DIM];
    int tid = threadIdx.x;
    for (int i = tid; i < DIM * DIM; i += blockDim.x) Ws[i] = W[i];
    __syncthreads();
    int row = blockIdx.x * (blockDim.x / DIM) + (tid >> 5);
    int col = tid & 31;
    if (row < n) {
        const float* xr = x + row * DIM;
        float s = 0.f;
#pragma unroll
        for (int k = 0; k < DIM; ++k) s += xr[k] * Ws[k * DIM + col];
        hs[row * DIM + col] = s * dis[row];
    }
}

// ---- aggregate: one block per bucket, 8 waves, software-pipelined gather ----
__global__ __launch_bounds__(512) void agg_kernel(
        const unsigned int* __restrict__ packedF, const int* __restrict__ rowptr,
        const float* __restrict__ hs, const float* __restrict__ dis,
        const float* __restrict__ bias, float* __restrict__ out, int N) {
    __shared__ float accum[BDST * DIM];  // 8 KB
    int t = threadIdx.x;
    for (int i = t; i < BDST * DIM; i += 512) accum[i] = 0.f;
    __syncthreads();

    int b = blockIdx.x;
    int start = rowptr[b * BDST];
    int end = rowptr[min(b * BDST + BDST, N)];
    int len = end - start;
    int wave = t >> 6, lane = t & 63, g = lane >> 5, f = lane & 31;
    int q = (len + 7) >> 3;
    int ws = start + wave * q;
    int we = min(ws + q, end);

    // 8 edges per wave-iteration (4 slots x 2 lane-groups), next-iter prefetch
    unsigned int p[4]; bool val[4];
    int j = ws;
#pragma unroll
    for (int u = 0; u < 4; ++u) {
        int idx = j + 2 * u + g;
        val[u] = idx < we;
        p[u] = val[u] ? packedF[idx] : 0u;
    }
    while (j < we) {
        int jn = j + 8;
        unsigned int pn[4]; bool valn[4];
#pragma unroll
        for (int u = 0; u < 4; ++u) {
            int idx = jn + 2 * u + g;
            valn[u] = idx < we;
            pn[u] = valn[u] ? packedF[idx] : 0u;
        }
        float h[4];
#pragma unroll
        for (int u = 0; u < 4; ++u)
            h[u] = val[u] ? hs[(size_t)(p[u] >> BSH) * DIM + f] : 0.f;
#pragma unroll
        for (int u = 0; u < 4; ++u)
            if (val[u]) atomicAdd(&accum[(p[u] & (BDST - 1)) * DIM + f], h[u]);
        j = jn;
#pragma unroll
        for (int u = 0; u < 4; ++u) { p[u] = pn[u]; val[u] = valn[u]; }
    }
    __syncthreads();

    // epilogue: 16 dsts x 32 feats per iteration
    int grp = t >> 5;  // 0..15
    float bf = bias[f];
    for (int r = 0; r < BDST / 16; ++r) {
        int dL = r * 16 + grp;
        int d = b * BDST + dL;
        if (d < N) {
            float v = dis[d] * (accum[dL * DIM + f] + hs[(size_t)d * DIM + f]) + bf;
            float s1 = v, s2 = v * v;
#pragma unroll
            for (int off = 16; off > 0; off >>= 1) {
                s1 += __shfl_xor(s1, off, 32);
                s2 += __shfl_xor(s2, off, 32);
            }
            float mean = s1 * (1.0f / 32.0f);
            float var = fmaxf(s2 * (1.0f / 32.0f) - mean * mean, 0.f);
            float o = (v - mean) * rsqrtf(var + 1e-6f);
            out[(size_t)d * DIM + f] = (o >= 0.f) ? o : 0.01f * o;
        }
    }
}

extern "C" void kernel_launch(void* const* d_in, const int* in_sizes, int n_in,
                              void* d_out, int out_size, void* d_ws, size_t ws_size,
                              hipStream_t stream) {
    const float* x = (const float*)d_in[0];
    const int* edge_index = (const int*)d_in[1];
    const float* W = (const float*)d_in[2];
    const float* b = (const float*)d_in[3];
    float* out = (float*)d_out;

    const int N = in_sizes[0] / DIM;      // 100000
    const int E = in_sizes[1] / 2;        // 1600000
    const int* src = edge_index;
    const int* dst = edge_index + E;

    const int NB = (N + BDST - 1) / BDST;       // 1563 buckets
    const int nblkA = (E + EPB - 1) / EPB;      // 196 chunks
    const int NBLK = (N + SCAN_B - 1) / SCAN_B; // 391

    char* w = (char*)d_ws;
    float* hs              = (float*)w;          w += (size_t)N * DIM * sizeof(float);
    unsigned int* packed   = (unsigned int*)w;   w += (size_t)E * sizeof(unsigned int);
    unsigned int* packedF  = (unsigned int*)w;   w += (size_t)E * sizeof(unsigned int);
    unsigned int* gofs     = (unsigned int*)w;   w += (size_t)nblkA * NB * sizeof(unsigned int);
    unsigned short* bucketId = (unsigned short*)w; w += (((size_t)E * 2 + 3) & ~(size_t)3);
    unsigned short* tbl    = (unsigned short*)w; w += (((size_t)nblkA * (NB + 1) * 2 + 3) & ~(size_t)3);
    unsigned short* cnts   = (unsigned short*)w; w += (((size_t)nblkA * NB * 2 + 3) & ~(size_t)3);
    int* deg     = (int*)w;   w += (size_t)N * sizeof(int);
    int* rowptr  = (int*)w;   w += (size_t)(N + 1) * sizeof(int);
    float* dis   = (float*)w; w += (size_t)N * sizeof(float);
    int* partials = (int*)w;  w += 1024 * sizeof(int);

    zero_kernel<<<(N + 255) / 256, 256, 0, stream>>>(deg, N);
    binA_kernel<<<nblkA, 256, 0, stream>>>(src, dst, deg, packed, bucketId, tbl, cnts, E, NB);
    partial_kernel<<<NBLK, SCAN_B, 0, stream>>>(deg, partials, N);
    scan_partials_kernel<<<1, 512, 0, stream>>>(partials, NBLK);
    scan_kernel<<<NBLK, SCAN_B, 0, stream>>>(deg, partials, rowptr, dis, N);
    gofs_kernel<<<(NB + 3) / 4, 256, 0, stream>>>(cnts, rowptr, gofs, NB, nblkA);
    gemm_kernel<<<(N + 7) / 8, 256, 0, stream>>>(x, W, dis, hs, N);
    copyout_kernel<<<nblkA, 256, 0, stream>>>(packed, bucketId, tbl, gofs, packedF, E, NB);
    agg_kernel<<<NB, 512, 0, stream>>>(packedF, rowptr, hs, dis, b, out, N);
}

// Round 9
// 240.426 us; speedup vs baseline: 2.2717x; 2.1293x over previous
//
#include <hip/hip_runtime.h>
#include <hip/hip_fp16.h>

#define DIM 32

typedef _Float16 h2v __attribute__((ext_vector_type(2)));

__global__ void zero_kernel(unsigned int* __restrict__ p, int n) {
    int i = blockIdx.x * blockDim.x + threadIdx.x;
    if (i < n) p[i] = 0u;
}

__global__ void deg_kernel(const int* __restrict__ dst, int* __restrict__ deg, int E) {
    int e = blockIdx.x * blockDim.x + threadIdx.x;
    if (e < E) atomicAdd(&deg[dst[e]], 1);
}

// hs[row] = half2((x @ W)[row] * rsqrt(deg[row]+1)); 2 features per thread
__global__ __launch_bounds__(256) void gemm_kernel(
        const float* __restrict__ x, const float* __restrict__ W,
        const int* __restrict__ deg, __half2* __restrict__ hs, int n) {
    __shared__ float Ws[DIM * DIM];
    int t = threadIdx.x;
    for (int i = t; i < DIM * DIM; i += 256) Ws[i] = W[i];
    __syncthreads();
    int row = blockIdx.x * 16 + (t >> 4);
    int c0 = (t & 15) * 2;
    if (row < n) {
        const float* xr = x + (size_t)row * DIM;
        float s0 = 0.f, s1 = 0.f;
#pragma unroll
        for (int k = 0; k < DIM; ++k) {
            float xv = xr[k];
            s0 += xv * Ws[k * DIM + c0];
            s1 += xv * Ws[k * DIM + c0 + 1];
        }
        float di = rsqrtf((float)deg[row] + 1.0f);
        hs[(size_t)row * 16 + (t & 15)] = __floats2half2_rn(s0 * di, s1 * di);
    }
}

__device__ __forceinline__ void pk_fadd_h2(__half2* addr, __half2 val) {
#if defined(__HIP_DEVICE_COMPILE__)
#if __has_builtin(__builtin_amdgcn_global_atomic_fadd_v2f16)
    __builtin_amdgcn_global_atomic_fadd_v2f16((h2v*)addr, *(h2v*)&val);
#else
    // CAS fallback
    unsigned int* p = (unsigned int*)addr;
    unsigned int old = *p, assumed;
    do {
        assumed = old;
        __half2 cur = *(__half2*)&assumed;
        __half2 sum = __hadd2(cur, val);
        old = atomicCAS(p, assumed, *(unsigned int*)&sum);
    } while (old != assumed);
#endif
#endif
}

// accum[d] += hs[s] : 16 lanes/edge, one 4B pk_add_f16 atomic per lane
__global__ __launch_bounds__(256) void scatter_kernel(
        const int* __restrict__ src, const int* __restrict__ dst,
        const __half2* __restrict__ hs, __half2* __restrict__ accum, int E) {
    int t = blockIdx.x * blockDim.x + threadIdx.x;
    int e = t >> 4;
    int f = t & 15;
    if (e < E) {
        int s = src[e], d = dst[e];
        __half2 val = hs[(size_t)s * 16 + f];
        pk_fadd_h2(&accum[(size_t)d * 16 + f], val);
    }
}

// out = leakyrelu(nodenorm(dis*(accum + hs_self) + b)) : 16 lanes/node, 2 feats/lane
__global__ __launch_bounds__(256) void final_kernel(
        const __half2* __restrict__ accum, const __half2* __restrict__ hs,
        const int* __restrict__ deg, const float* __restrict__ b,
        float2* __restrict__ out, int n) {
    int t = blockIdx.x * blockDim.x + threadIdx.x;
    int i = t >> 4;
    int f = t & 15;
    if (i >= n) return;
    float2 a = __half22float2(accum[(size_t)i * 16 + f]);
    float2 h = __half22float2(hs[(size_t)i * 16 + f]);
    float di = rsqrtf((float)deg[i] + 1.0f);
    float v0 = di * (a.x + h.x) + b[2 * f];
    float v1 = di * (a.y + h.y) + b[2 * f + 1];
    float s1 = v0 + v1, s2 = v0 * v0 + v1 * v1;
#pragma unroll
    for (int off = 8; off > 0; off >>= 1) {
        s1 += __shfl_xor(s1, off, 16);
        s2 += __shfl_xor(s2, off, 16);
    }
    float mean = s1 * (1.0f / 32.0f);
    float var = fmaxf(s2 * (1.0f / 32.0f) - mean * mean, 0.f);
    float rs = rsqrtf(var + 1e-6f);
    float o0 = (v0 - mean) * rs;
    float o1 = (v1 - mean) * rs;
    float2 o;
    o.x = (o0 >= 0.f) ? o0 : 0.01f * o0;
    o.y = (o1 >= 0.f) ? o1 : 0.01f * o1;
    out[(size_t)i * 16 + f] = o;
}

extern "C" void kernel_launch(void* const* d_in, const int* in_sizes, int n_in,
                              void* d_out, int out_size, void* d_ws, size_t ws_size,
                              hipStream_t stream) {
    const float* x = (const float*)d_in[0];
    const int* edge_index = (const int*)d_in[1];
    const float* W = (const float*)d_in[2];
    const float* b = (const float*)d_in[3];
    float2* out = (float2*)d_out;

    const int N = in_sizes[0] / DIM;      // 100000
    const int E = in_sizes[1] / 2;        // 1600000
    const int* src = edge_index;
    const int* dst = edge_index + E;

    // layout: accum (N*16 half2 = N*16 dwords) | deg (N dwords) | hs (N*16 half2)
    char* w = (char*)d_ws;
    __half2* accum = (__half2*)w;               w += (size_t)N * 16 * sizeof(__half2);
    int* deg       = (int*)w;                   w += (size_t)N * sizeof(int);
    __half2* hs    = (__half2*)w;               w += (size_t)N * 16 * sizeof(__half2);

    // zero accum + deg in one pass (contiguous dwords)
    const int nzero = N * 16 + N;
    zero_kernel<<<(nzero + 255) / 256, 256, 0, stream>>>((unsigned int*)accum, nzero);
    deg_kernel<<<(E + 255) / 256, 256, 0, stream>>>(dst, deg, E);
    gemm_kernel<<<(N + 15) / 16, 256, 0, stream>>>(x, W, deg, hs, N);
    scatter_kernel<<<((size_t)E * 16 + 255) / 256, 256, 0, stream>>>(src, dst, hs, accum, E);
    final_kernel<<<(N * 16 + 255) / 256, 256, 0, stream>>>(accum, hs, deg, b, out, N);
}